// Round 10
// baseline (637.313 us; speedup 1.0000x reference)
//
#include <hip/hip_runtime.h>

// LSTM cell, B=8192, IN=H=2048, fp32 in/out.
// Round 10: 32x32x16 MFMA (2495 TF family vs 2176 for 16x16x32).
// Per-wave 128x64 = 4m x 2n frags of 32x32. LDS quarters: q0=A kh0, q1=B kh0,
// q2=A kh1, q3=B kh1, each [256 rows][32 K] bf16 with 3-bit pair-swizzle:
//   byte(row,ks) = (row>>1)*128 + (((row&1)*4+ks) ^ ((row>>1)&7))*16
// (involution; applied inverse on GLDS source, forward on ds_read).
// Phases = K16 steps kk0..3: 6 ds_read_b128 + stage q_kk(t+1) + [vmcnt(4) at
// ph1,ph3] + barrier + 8 MFMA (setprio-wrapped). Steady-state vmcnt 4<->8.
// Epilogue: C frag spans 2 gates (16 cols each) -> shfl_xor(16) pairs lanes,
// bit4=0 lanes hold f,o / bit4=1 hold i,c; both compute, split h/c stores.
// Pack: X2 bf16 [8192][4096] = [x|h];  W3 bf16 [8192][4096] with row
//   j = (hc>>4)*64 + gate*16 + (hc&15).

typedef __attribute__((ext_vector_type(8))) short short8;
typedef __attribute__((ext_vector_type(8))) __bf16 bf16x8;
typedef __attribute__((ext_vector_type(16))) float f32x16;

#define GLDS(gp, lp)                                                        \
  __builtin_amdgcn_global_load_lds(                                         \
      (const __attribute__((address_space(1))) void*)(gp),                  \
      (__attribute__((address_space(3))) void*)(lp), 16, 0, 0)

__device__ __forceinline__ unsigned short f2bf(float f) {
  unsigned u = __builtin_bit_cast(unsigned, f);
  u = (u + 0x7FFFu + ((u >> 16) & 1u)) >> 16;  // RNE
  return (unsigned short)u;
}

// ---- pack [x | h] -> X2 bf16 [8192][4096] ----
__global__ void pack_x_kernel(const float* __restrict__ x,
                              const float* __restrict__ h,
                              short* __restrict__ X2) {
  long tid = (long)blockIdx.x * blockDim.x + threadIdx.x;
  long flat = tid * 8;
  int row = (int)(flat >> 12);
  int k = (int)(flat & 4095);
  const float* src = (k < 2048) ? (x + (long)row * 2048 + k)
                                : (h + (long)row * 2048 + (k - 2048));
  float4 a = *(const float4*)src;
  float4 b = *(const float4*)(src + 4);
  short8 o;
  o[0] = (short)f2bf(a.x); o[1] = (short)f2bf(a.y);
  o[2] = (short)f2bf(a.z); o[3] = (short)f2bf(a.w);
  o[4] = (short)f2bf(b.x); o[5] = (short)f2bf(b.y);
  o[6] = (short)f2bf(b.z); o[7] = (short)f2bf(b.w);
  *(short8*)(X2 + flat) = o;
}

// ---- pack weights -> W3 bf16 [8192][4096]; row j: hc=(j>>6)*16+(j&15), g=(j>>4)&3 ----
__global__ void pack_w_kernel(const float* __restrict__ wxf, const float* __restrict__ wxi,
                              const float* __restrict__ wxo, const float* __restrict__ wxc,
                              const float* __restrict__ whf, const float* __restrict__ whi,
                              const float* __restrict__ who, const float* __restrict__ whc,
                              short* __restrict__ W3) {
  long tid = (long)blockIdx.x * blockDim.x + threadIdx.x;
  long flat = tid * 8;
  int j = (int)(flat >> 12);
  int k = (int)(flat & 4095);
  int hc = ((j >> 6) << 4) | (j & 15);
  int g = (j >> 4) & 3;
  const float* base;
  if (k < 2048) {
    const float* wx = (g == 0) ? wxf : (g == 1) ? wxi : (g == 2) ? wxo : wxc;
    base = wx + (long)hc * 2048 + k;
  } else {
    const float* wh = (g == 0) ? whf : (g == 1) ? whi : (g == 2) ? who : whc;
    base = wh + (long)hc * 2048 + (k - 2048);
  }
  float4 a = *(const float4*)base;
  float4 b = *(const float4*)(base + 4);
  short8 o;
  o[0] = (short)f2bf(a.x); o[1] = (short)f2bf(a.y);
  o[2] = (short)f2bf(a.z); o[3] = (short)f2bf(a.w);
  o[4] = (short)f2bf(b.x); o[5] = (short)f2bf(b.y);
  o[6] = (short)f2bf(b.z); o[7] = (short)f2bf(b.w);
  *(short8*)(W3 + flat) = o;
}

// ---- 256x256 fused GEMM (32x32x16) + LSTM epilogue ----
__global__ __launch_bounds__(512, 2) void lstm_fused_gemm(
    const short* __restrict__ X2, const short* __restrict__ W3,
    const float* __restrict__ cin,
    const float* __restrict__ bF, const float* __restrict__ bI,
    const float* __restrict__ bO, const float* __restrict__ bC,
    float* __restrict__ hout, float* __restrict__ cout_) {
  __shared__ __align__(16) short lds[65536];  // 128 KiB

  const int tid = threadIdx.x;
  const int lane = tid & 63;
  const int w = tid >> 6;        // 0..7
  const int wm = w >> 2;         // 0..1  (M half, 128 rows)
  const int wn = w & 3;          // 0..3  (N quarter, 64 cols)

  // XCD super-tile (1024 blocks): 32 co-resident blocks/XCD = 4 bM x 8 bN.
  const int bid = blockIdx.x;
  const int bM = (bid & 7) * 4 + ((bid >> 3) & 3);  // 0..31
  const int bN = bid >> 5;                          // 0..31

  // --- staging geometry (pair-swizzle inverse on source) ---
  // chunk c (of 1024/region): pair=c>>3, Sphys=c&7, Slog=Sphys^(pair&7),
  // srow=pair*2+(Slog>>2), kchunk=Slog&3. Thread handles c=tid and c=tid+512
  // (same Slog; srow+128).
  const int sPair = tid >> 3;
  const int sSlog = (tid & 7) ^ (sPair & 7);
  const int srow = sPair * 2 + (sSlog >> 2);        // 0..127
  const int skoff = (sSlog & 3) * 8;                // bf16 elems
  const short* aRow0 = X2 + ((size_t)(bM * 256 + srow)) * 4096 + skoff;
  const short* aRow1 = aRow0 + (size_t)128 * 4096;
  const short* bRow0 = W3 + ((size_t)(bN * 256 + srow)) * 4096 + skoff;
  const short* bRow1 = bRow0 + (size_t)128 * 4096;

#define STAGEQ(q, tt, bb) do {                                               \
    const int _kh = (q) >> 1;                                                \
    const short* _g0; const short* _g1;                                      \
    if (((q) & 1) == 0) {                                                    \
      _g0 = aRow0 + (tt) * 64 + _kh * 32;                                    \
      _g1 = aRow1 + (tt) * 64 + _kh * 32;                                    \
    } else {                                                                 \
      _g0 = bRow0 + (tt) * 64 + _kh * 32;                                    \
      _g1 = bRow1 + (tt) * 64 + _kh * 32;                                    \
    }                                                                        \
    char* _l0 = (char*)lds + (bb) * 65536 + (q) * 16384 + tid * 16;          \
    GLDS(_g0, _l0);                                                          \
    GLDS(_g1, _l0 + 8192);                                                   \
  } while (0)

  // --- ds_read geometry (pair-swizzle forward) ---
  // A row for frag m: rA + m*32 (rA = wm*128 + (lane&31)); m*32 keeps
  // (row>>1)&7 and row&1 invariant -> per-lane constant swizzle.
  const int l31 = lane & 31, hi2 = lane >> 5;
  const int rA = wm * 128 + l31;
  const int pA = rA >> 1;
  const int aoffE = pA * 128 + ((((rA & 1) * 4) + 0 + hi2) ^ (pA & 7)) * 16;
  const int aoffO = pA * 128 + ((((rA & 1) * 4) + 2 + hi2) ^ (pA & 7)) * 16;
  const int rB = wn * 64 + l31;
  const int pB = rB >> 1;
  const int boffE = 16384 + pB * 128 + ((((rB & 1) * 4) + 0 + hi2) ^ (pB & 7)) * 16;
  const int boffO = 16384 + pB * 128 + ((((rB & 1) * 4) + 2 + hi2) ^ (pB & 7)) * 16;

#define LDSRD(off) (*(const bf16x8*)((const char*)lds + (off)))
#define MFMA32(a, b, c) __builtin_amdgcn_mfma_f32_32x32x16_bf16((a), (b), (c), 0, 0, 0)

  f32x16 acc[4][2] = {};  // [m][n]; frag n spans gates {2n, 2n+1}

  // --- prologue: tile0 -> buf0 (8 GLDS); drain; barrier ---
  STAGEQ(0, 0, 0); STAGEQ(1, 0, 0); STAGEQ(2, 0, 0); STAGEQ(3, 0, 0);
  asm volatile("s_waitcnt vmcnt(0)" ::: "memory");
  __builtin_amdgcn_s_barrier();

#pragma unroll 2
  for (int t = 0; t < 64; ++t) {
    const int cur = t & 1, nxt = cur ^ 1;
    const int bo = cur << 16;
    const int t1 = (t + 1) & 63;   // t=63 stages dummy (never read; safe)
    bf16x8 a[4], b[2];

    // ---- ph0 (kk0: kh0,E): 6 reads; stage q0(t+1)->nxt ----
#pragma unroll
    for (int m = 0; m < 4; ++m) a[m] = LDSRD(bo + aoffE + m * 2048);
#pragma unroll
    for (int n = 0; n < 2; ++n) b[n] = LDSRD(bo + boffE + n * 2048);
    STAGEQ(0, t1, nxt);
    __builtin_amdgcn_s_barrier();
    __builtin_amdgcn_s_setprio(1);
#pragma unroll
    for (int n = 0; n < 2; ++n)
#pragma unroll
      for (int m = 0; m < 4; ++m) acc[m][n] = MFMA32(a[m], b[n], acc[m][n]);
    __builtin_amdgcn_s_setprio(0);

    // ---- ph1 (kk1: kh0,O): 6 reads; stage q1(t+1); vmcnt(4) ----
#pragma unroll
    for (int m = 0; m < 4; ++m) a[m] = LDSRD(bo + aoffO + m * 2048);
#pragma unroll
    for (int n = 0; n < 2; ++n) b[n] = LDSRD(bo + boffO + n * 2048);
    STAGEQ(1, t1, nxt);
    asm volatile("s_waitcnt vmcnt(4)" ::: "memory");   // cur q2,q3 landed
    __builtin_amdgcn_s_barrier();
    __builtin_amdgcn_s_setprio(1);
#pragma unroll
    for (int n = 0; n < 2; ++n)
#pragma unroll
      for (int m = 0; m < 4; ++m) acc[m][n] = MFMA32(a[m], b[n], acc[m][n]);
    __builtin_amdgcn_s_setprio(0);

    // ---- ph2 (kk2: kh1,E): 6 reads; stage q2(t+1) ----
#pragma unroll
    for (int m = 0; m < 4; ++m) a[m] = LDSRD(bo + 32768 + aoffE + m * 2048);
#pragma unroll
    for (int n = 0; n < 2; ++n) b[n] = LDSRD(bo + 32768 + boffE + n * 2048);
    STAGEQ(2, t1, nxt);
    __builtin_amdgcn_s_barrier();
    __builtin_amdgcn_s_setprio(1);
#pragma unroll
    for (int n = 0; n < 2; ++n)
#pragma unroll
      for (int m = 0; m < 4; ++m) acc[m][n] = MFMA32(a[m], b[n], acc[m][n]);
    __builtin_amdgcn_s_setprio(0);

    // ---- ph3 (kk3: kh1,O): 6 reads; stage q3(t+1); vmcnt(4) ----
#pragma unroll
    for (int m = 0; m < 4; ++m) a[m] = LDSRD(bo + 32768 + aoffO + m * 2048);
#pragma unroll
    for (int n = 0; n < 2; ++n) b[n] = LDSRD(bo + 32768 + boffO + n * 2048);
    STAGEQ(3, t1, nxt);
    asm volatile("s_waitcnt vmcnt(4)" ::: "memory");   // nxt q0,q1 landed
    __builtin_amdgcn_s_barrier();
    __builtin_amdgcn_s_setprio(1);
#pragma unroll
    for (int n = 0; n < 2; ++n)
#pragma unroll
      for (int m = 0; m < 4; ++m) acc[m][n] = MFMA32(a[m], b[n], acc[m][n]);
    __builtin_amdgcn_s_setprio(0);
  }

  // ---- fused LSTM epilogue ----
  // C frag: col = lane&31, row = (reg&3)+8*(reg>>2)+4*(lane>>5).
  // gate(n, bit4) = 2n + bit4; hc = (bN*4+wn)*16 + (lane&15) for all n.
  const int l15 = lane & 15;
  const int bit4 = (lane >> 4) & 1;
  const int hc = (bN * 4 + wn) * 16 + l15;
  const float vbF = bF[hc], vbI = bI[hc], vbO = bO[hc], vbC = bC[hc];
  float* const cPtr = cout_;
#pragma unroll
  for (int m = 0; m < 4; ++m) {
    const int rowbase = bM * 256 + wm * 128 + m * 32 + 4 * hi2;
#pragma unroll
    for (int r = 0; r < 16; ++r) {
      const int rowg = rowbase + (r & 3) + 8 * (r >> 2);
      const float a0 = acc[m][0][r];       // f (bit4=0) or i (bit4=1)
      const float a1 = acc[m][1][r];       // o (bit4=0) or c (bit4=1)
      const float s0 = __shfl_xor(a0, 16);
      const float s1 = __shfl_xor(a1, 16);
      const float gf = (bit4 ? s0 : a0) + vbF;
      const float gi = (bit4 ? a0 : s0) + vbI;
      const float go = (bit4 ? s1 : a1) + vbO;
      const float gc = (bit4 ? a1 : s1) + vbC;
      const float fg = 1.f / (1.f + __expf(-gf));
      const float ig = 1.f / (1.f + __expf(-gi));
      const float og = 1.f / (1.f + __expf(-go));
      const float ct = 2.f / (1.f + __expf(-2.f * gc)) - 1.f;
      const size_t idx = (size_t)rowg * 2048 + hc;
      const float cn = fg * cin[idx] + ig * ct;
      const float hn = og * (2.f / (1.f + __expf(-2.f * cn)) - 1.f);
      float* dst = bit4 ? cPtr : hout;
      dst[idx] = bit4 ? cn : hn;
    }
  }
}

extern "C" void kernel_launch(void* const* d_in, const int* in_sizes, int n_in,
                              void* d_out, int out_size, void* d_ws, size_t ws_size,
                              hipStream_t stream) {
  const float* x    = (const float*)d_in[0];
  const float* h    = (const float*)d_in[1];
  const float* c    = (const float*)d_in[2];
  const float* w_xf = (const float*)d_in[3];
  const float* w_hf = (const float*)d_in[4];
  const float* b_f  = (const float*)d_in[5];
  const float* w_xi = (const float*)d_in[6];
  const float* w_hi = (const float*)d_in[7];
  const float* b_i  = (const float*)d_in[8];
  const float* w_xo = (const float*)d_in[9];
  const float* w_ho = (const float*)d_in[10];
  const float* b_o  = (const float*)d_in[11];
  const float* w_xc = (const float*)d_in[12];
  const float* w_hc = (const float*)d_in[13];
  const float* b_c  = (const float*)d_in[14];

  float* hout  = (float*)d_out;
  float* cout_ = hout + (size_t)8192 * 2048;

  short* X2 = (short*)d_ws;                       // 64 MiB
  short* W3 = X2 + (size_t)8192 * 4096;           // 64 MiB

  const int packBlocks = (int)(((long)8192 * 4096 / 8) / 256);  // 16384
  pack_x_kernel<<<packBlocks, 256, 0, stream>>>(x, h, X2);
  pack_w_kernel<<<packBlocks, 256, 0, stream>>>(w_xf, w_xi, w_xo, w_xc,
                                                w_hf, w_hi, w_ho, w_hc, W3);

  lstm_fused_gemm<<<1024, 512, 0, stream>>>(X2, W3, c, b_f, b_i, b_o, b_c,
                                            hout, cout_);
}